// Round 1
// baseline (89.682 us; speedup 1.0000x reference)
//
#include <hip/hip_runtime.h>

// x: (64, 256, 56, 56) f32. Per (b,c): mag = sum(x^2). Per batch: threshold =
// 128th largest mag; keep channels with mag > threshold (strict), zero others.

#define B 64
#define C 256
#define PLANE 3136       // 56*56
#define PLANE4 784       // 3136/4
#define KCH 128          // NUM_CHANNELS

// ---------------- Kernel 1: per-plane sum of squares ----------------
__global__ __launch_bounds__(256) void mag_kernel(const float* __restrict__ x,
                                                  float* __restrict__ mag) {
    const int plane = blockIdx.x;  // b*C + c
    const float4* __restrict__ xp =
        reinterpret_cast<const float4*>(x + (size_t)plane * PLANE);
    float s = 0.f;
    for (int i = threadIdx.x; i < PLANE4; i += 256) {
        float4 v = xp[i];
        s = fmaf(v.x, v.x, s);
        s = fmaf(v.y, v.y, s);
        s = fmaf(v.z, v.z, s);
        s = fmaf(v.w, v.w, s);
    }
    // wave64 butterfly reduce
    for (int off = 32; off > 0; off >>= 1) s += __shfl_down(s, off, 64);
    __shared__ float ws4[4];
    const int lane = threadIdx.x & 63;
    const int wid  = threadIdx.x >> 6;
    if (lane == 0) ws4[wid] = s;
    __syncthreads();
    if (threadIdx.x == 0) {
        mag[plane] = (ws4[0] + ws4[1]) + (ws4[2] + ws4[3]);
    }
}

// ---------------- Kernel 2: per-batch rank-128 threshold ----------------
// threshold = sorted_desc[KCH-1]. Value v is it iff
//   (#values > v) <= KCH-1  and  KCH-1 < (#values > v) + (#values == v)
__global__ __launch_bounds__(256) void thr_kernel(const float* __restrict__ mag,
                                                  float* __restrict__ thr) {
    __shared__ float m[C];
    const int b = blockIdx.x;
    const float v = mag[b * C + threadIdx.x];
    m[threadIdx.x] = v;
    __syncthreads();
    int gt = 0, eq = 0;
    for (int i = 0; i < C; ++i) {
        float mi = m[i];
        gt += (mi > v);
        eq += (mi == v);
    }
    if (gt <= (KCH - 1) && (KCH - 1) < gt + eq) {
        thr[b] = v;  // possibly multiple writers of the SAME value — benign
    }
}

// ---------------- Kernel 3: masked copy / zero ----------------
__global__ __launch_bounds__(256) void write_kernel(const float* __restrict__ x,
                                                    const float* __restrict__ mag,
                                                    const float* __restrict__ thr,
                                                    float* __restrict__ y) {
    const int plane = blockIdx.x;
    const int b = plane >> 8;  // /C
    const bool keep = mag[plane] > thr[b];
    const float4* __restrict__ xp =
        reinterpret_cast<const float4*>(x + (size_t)plane * PLANE);
    float4* __restrict__ yp = reinterpret_cast<float4*>(y + (size_t)plane * PLANE);
    if (keep) {
        for (int i = threadIdx.x; i < PLANE4; i += 256) yp[i] = xp[i];
    } else {
        const float4 z = {0.f, 0.f, 0.f, 0.f};
        for (int i = threadIdx.x; i < PLANE4; i += 256) yp[i] = z;
    }
}

extern "C" void kernel_launch(void* const* d_in, const int* in_sizes, int n_in,
                              void* d_out, int out_size, void* d_ws, size_t ws_size,
                              hipStream_t stream) {
    const float* x = (const float*)d_in[0];
    float* y = (float*)d_out;
    float* mag = (float*)d_ws;        // B*C floats = 64 KB
    float* thr = mag + B * C;         // B floats

    mag_kernel<<<B * C, 256, 0, stream>>>(x, mag);
    thr_kernel<<<B, 256, 0, stream>>>(mag, thr);
    write_kernel<<<B * C, 256, 0, stream>>>(x, mag, thr, y);
}

// Round 2
// 84.387 us; speedup vs baseline: 1.0627x; 1.0627x over previous
//
#include <hip/hip_runtime.h>

// x: (64, 256, 56, 56) f32. Per (b,c): mag = sum(x^2). Per batch: keep channel
// iff count(mags in batch >= own mag) <= 127  (== mag > 128th-largest, tie-exact).

#define B 64
#define C 256
#define PLANE 3136       // 56*56
#define PLANE4 784       // 3136/4
#define KCH 128          // NUM_CHANNELS

// ---------------- Kernel 1: per-plane sum of squares ----------------
__global__ __launch_bounds__(256) void mag_kernel(const float* __restrict__ x,
                                                  float* __restrict__ mag) {
    const int plane = blockIdx.x;  // b*C + c
    const float4* __restrict__ xp =
        reinterpret_cast<const float4*>(x + (size_t)plane * PLANE);
    float s = 0.f;
    for (int i = threadIdx.x; i < PLANE4; i += 256) {
        float4 v = xp[i];
        s = fmaf(v.x, v.x, s);
        s = fmaf(v.y, v.y, s);
        s = fmaf(v.z, v.z, s);
        s = fmaf(v.w, v.w, s);
    }
    // wave64 reduce
    for (int off = 32; off > 0; off >>= 1) s += __shfl_down(s, off, 64);
    __shared__ float ws4[4];
    const int lane = threadIdx.x & 63;
    const int wid  = threadIdx.x >> 6;
    if (lane == 0) ws4[wid] = s;
    __syncthreads();
    if (threadIdx.x == 0) {
        mag[plane] = (ws4[0] + ws4[1]) + (ws4[2] + ws4[3]);
    }
}

// ---------------- Kernel 2: rank test + masked copy / zero ----------------
__global__ __launch_bounds__(256) void write_kernel(const float* __restrict__ x,
                                                    const float* __restrict__ mag,
                                                    float* __restrict__ y) {
    const int plane = blockIdx.x;
    const int base  = plane & ~(C - 1);   // start of this batch's 256 mags

    // keep iff count(mags >= own) <= KCH-1
    __shared__ int cnts[4];
    const float m_own = mag[plane];
    const float mt    = mag[base + threadIdx.x];
    const unsigned long long ball = __ballot(mt >= m_own);
    const int lane = threadIdx.x & 63;
    const int wid  = threadIdx.x >> 6;
    if (lane == 0) cnts[wid] = __popcll(ball);
    __syncthreads();
    const bool keep = (cnts[0] + cnts[1] + cnts[2] + cnts[3]) <= (KCH - 1);

    const float4* __restrict__ xp =
        reinterpret_cast<const float4*>(x + (size_t)plane * PLANE);
    float4* __restrict__ yp = reinterpret_cast<float4*>(y + (size_t)plane * PLANE);
    if (keep) {
        for (int i = threadIdx.x; i < PLANE4; i += 256) yp[i] = xp[i];
    } else {
        const float4 z = {0.f, 0.f, 0.f, 0.f};
        for (int i = threadIdx.x; i < PLANE4; i += 256) yp[i] = z;
    }
}

extern "C" void kernel_launch(void* const* d_in, const int* in_sizes, int n_in,
                              void* d_out, int out_size, void* d_ws, size_t ws_size,
                              hipStream_t stream) {
    const float* x = (const float*)d_in[0];
    float* y = (float*)d_out;
    float* mag = (float*)d_ws;        // B*C floats = 64 KB

    mag_kernel<<<B * C, 256, 0, stream>>>(x, mag);
    write_kernel<<<B * C, 256, 0, stream>>>(x, mag, y);
}

// Round 4
// 75.225 us; speedup vs baseline: 1.1922x; 1.1218x over previous
//
#include <hip/hip_runtime.h>

// x: (64, 256, 56, 56) f32. Per (b,c): mag = sum(x^2). Per batch: keep channel
// iff count(mags in batch >= own mag) <= 127  (== mag > 128th-largest, tie-exact).
// y writes use nontemporal stores: y is never re-read, keep x L3-resident.

#define B 64
#define C 256
#define PLANE 3136       // 56*56
#define PLANE4 784       // 3136/4
#define KCH 128          // NUM_CHANNELS

typedef float f32x4 __attribute__((ext_vector_type(4)));  // builtin-compatible

// ---------------- Kernel 1: per-plane sum of squares ----------------
__global__ __launch_bounds__(256) void mag_kernel(const float* __restrict__ x,
                                                  float* __restrict__ mag) {
    const int plane = blockIdx.x;  // b*C + c
    const f32x4* __restrict__ xp =
        reinterpret_cast<const f32x4*>(x + (size_t)plane * PLANE);
    float s = 0.f;
    for (int i = threadIdx.x; i < PLANE4; i += 256) {
        f32x4 v = xp[i];
        s = fmaf(v.x, v.x, s);
        s = fmaf(v.y, v.y, s);
        s = fmaf(v.z, v.z, s);
        s = fmaf(v.w, v.w, s);
    }
    // wave64 reduce
    for (int off = 32; off > 0; off >>= 1) s += __shfl_down(s, off, 64);
    __shared__ float ws4[4];
    const int lane = threadIdx.x & 63;
    const int wid  = threadIdx.x >> 6;
    if (lane == 0) ws4[wid] = s;
    __syncthreads();
    if (threadIdx.x == 0) {
        mag[plane] = (ws4[0] + ws4[1]) + (ws4[2] + ws4[3]);
    }
}

// ---------------- Kernel 2: rank test + masked copy / zero ----------------
__global__ __launch_bounds__(256) void write_kernel(const float* __restrict__ x,
                                                    const float* __restrict__ mag,
                                                    float* __restrict__ y) {
    const int plane = blockIdx.x;
    const int base  = plane & ~(C - 1);   // start of this batch's 256 mags

    // keep iff count(mags >= own) <= KCH-1
    __shared__ int cnts[4];
    const float m_own = mag[plane];
    const float mt    = mag[base + threadIdx.x];
    const unsigned long long ball = __ballot(mt >= m_own);
    const int lane = threadIdx.x & 63;
    const int wid  = threadIdx.x >> 6;
    if (lane == 0) cnts[wid] = __popcll(ball);
    __syncthreads();
    const bool keep = (cnts[0] + cnts[1] + cnts[2] + cnts[3]) <= (KCH - 1);

    const f32x4* __restrict__ xp =
        reinterpret_cast<const f32x4*>(x + (size_t)plane * PLANE);
    f32x4* __restrict__ yp = reinterpret_cast<f32x4*>(y + (size_t)plane * PLANE);
    if (keep) {
        for (int i = threadIdx.x; i < PLANE4; i += 256) {
            __builtin_nontemporal_store(xp[i], yp + i);
        }
    } else {
        const f32x4 z = {0.f, 0.f, 0.f, 0.f};
        for (int i = threadIdx.x; i < PLANE4; i += 256) {
            __builtin_nontemporal_store(z, yp + i);
        }
    }
}

extern "C" void kernel_launch(void* const* d_in, const int* in_sizes, int n_in,
                              void* d_out, int out_size, void* d_ws, size_t ws_size,
                              hipStream_t stream) {
    const float* x = (const float*)d_in[0];
    float* y = (float*)d_out;
    float* mag = (float*)d_ws;        // B*C floats = 64 KB

    mag_kernel<<<B * C, 256, 0, stream>>>(x, mag);
    write_kernel<<<B * C, 256, 0, stream>>>(x, mag, y);
}